// Round 3
// baseline (1681.025 us; speedup 1.0000x reference)
//
#include <hip/hip_runtime.h>
#include <hip/hip_cooperative_groups.h>
#include <math.h>

namespace cg = cooperative_groups;

#define T_DIM 32
#define H_DIM 1024
#define D_INNER 2048
#define NHEADS 32
#define DPROJ 4384       // 2*D_INNER + 2*D_STATE + NHEADS
#define ZX_SL 140288     // 32*4384, one k-slice of zx partials
#define OUT_SL 32768     // 32*1024, one k-slice of Wout partials

__device__ __forceinline__ float wave_sum(float v) {
#pragma unroll
    for (int off = 32; off > 0; off >>= 1) v += __shfl_xor(v, off, 64);
    return v;
}
__device__ __forceinline__ float sigf(float x) { return 1.f / (1.f + expf(-x)); }
__device__ __forceinline__ float siluf(float x) { return x / (1.f + expf(-x)); }
__device__ __forceinline__ float softplusf(float x) { return x > 20.f ? x : log1pf(expf(x)); }
// sum of 8 k-slice partials of zx
__device__ __forceinline__ float zxr(const float* __restrict__ zxp, int idx) {
    float a = 0.f;
#pragma unroll
    for (int s = 0; s < 8; s++) a += zxp[s * ZX_SL + idx];
    return a;
}

__global__ __launch_bounds__(256, 2) void mega(
    const float* __restrict__ x,   const float* __restrict__ w1, const float* __restrict__ b1,
    const float* __restrict__ w2,  const float* __restrict__ b2,
    const float* __restrict__ mWin, const float* __restrict__ mconvw, const float* __restrict__ mconvb,
    const float* __restrict__ mdtb, const float* __restrict__ mAlog, const float* __restrict__ mD,
    const float* __restrict__ mnw,  const float* __restrict__ mWout,
    const float* __restrict__ w3,  const float* __restrict__ b3,
    const float* __restrict__ w4,  const float* __restrict__ b4,
    float* __restrict__ out, float* __restrict__ ws) {
    __shared__ __align__(16) float lds[8192 + 96];  // 33KB: BC[32][256] | staging | reducers
    cg::grid_group grid = cg::this_grid();
    const int NBv = gridDim.x;
    const int NW = NBv * 4;             // total waves
    const int tid = threadIdx.x;
    const int bi = blockIdx.x;
    const int wid = tid >> 6, lane = tid & 63;
    const int gw = bi * 4 + wid;        // global wave id
    const int gtid = bi * 256 + tid;

    float* h1v  = ws;                   // 1024
    float* a3v  = ws + 1024;            // 1024
    float* seqA = ws + 2048;            // 32768
    float* yg   = ws + 34816;           // 65536
    float* psum = ws + 100352;          // 512*32
    float* zxp  = ws + 116736;          // 8 * 140288
    float* outp = ws + 1238528;         // 32 * 32768

    // ---- S1: h1 = relu(w1 @ x + b1)  (1024 rows, K=4096; wave per row) ----
    for (int r = gw; r < H_DIM; r += NW) {
        const float* wr = w1 + (size_t)r * 4096;
        float acc = 0.f;
        for (int k = lane * 4; k < 4096; k += 256) {
            float4 wv = *(const float4*)(wr + k);
            float4 xv = *(const float4*)(x + k);
            acc += wv.x * xv.x + wv.y * xv.y + wv.z * xv.z + wv.w * xv.w;
        }
        acc = wave_sum(acc);
        if (lane == 0) h1v[r] = fmaxf(acc + b1[r], 0.f);
    }
    grid.sync();

    // ---- S2: seqA = w2 @ h1 + b2  (32768 rows, K=1024; 2-row interleave per wave) ----
    for (int r = gw; r < 32768; r += 2 * NW) {
        const int r2 = r + NW;
        const bool has2 = r2 < 32768;
        const float* wr0 = w2 + (size_t)r * H_DIM;
        const float* wr1 = w2 + (size_t)(has2 ? r2 : r) * H_DIM;
        float a0 = 0.f, a1 = 0.f;
        for (int k = lane * 4; k < H_DIM; k += 256) {
            float4 xv = *(const float4*)(h1v + k);
            float4 v0 = *(const float4*)(wr0 + k);
            float4 v1 = *(const float4*)(wr1 + k);
            a0 += v0.x * xv.x + v0.y * xv.y + v0.z * xv.z + v0.w * xv.w;
            a1 += v1.x * xv.x + v1.y * xv.y + v1.z * xv.z + v1.w * xv.w;
        }
        a0 = wave_sum(a0); a1 = wave_sum(a1);
        if (lane == 0) {
            seqA[r] = a0 + b2[r];
            if (has2) seqA[r2] = a1 + b2[r2];
        }
    }
    grid.sync();

    // ---- layers ----
    for (int l = 0; l < 4; l++) {
        const float* Win  = mWin  + (size_t)l * DPROJ * H_DIM;
        const float* convw = mconvw + l * 2304 * 4;
        const float* convb = mconvb + l * 2304;
        const float* dtb  = mdtb  + l * NHEADS;
        const float* Alog = mAlog + l * NHEADS;
        const float* Dp   = mD    + l * NHEADS;
        const float* nw   = mnw   + l * D_INNER;
        const float* Wout = mWout + (size_t)l * H_DIM * D_INNER;

        // -- 3a: zx partials: zxp[ks][t][j] = Win[j, ks*128..+128) . U[t, ...] --
        for (int vb = bi; vb < 144; vb += NBv) {  // 8 k-slices * 18 j-blocks
            const int ks = vb / 18, jb = vb % 18;
            const int kbase = ks * 128;
            float4* Ul = (float4*)lds;        // [32][32] float4
            for (int i = tid; i < 1024; i += 256) {
                const int t = i >> 5, c4 = i & 31;
                float4 v;
                if (l == 0) {
                    v = *(const float4*)(seqA + t * H_DIM + kbase + c4 * 4);
                } else {  // fold 32-slice Wout-partial reduction into staging
                    v = make_float4(0.f, 0.f, 0.f, 0.f);
                    const float* op = outp + t * H_DIM + kbase + c4 * 4;
#pragma unroll 8
                    for (int s = 0; s < 32; s++) {
                        float4 o = *(const float4*)(op + s * OUT_SL);
                        v.x += o.x; v.y += o.y; v.z += o.z; v.w += o.w;
                    }
                }
                Ul[i] = v;
            }
            __syncthreads();
            const int j = jb * 256 + tid;
            if (j < DPROJ) {
                const float* wr = Win + (size_t)j * H_DIM + kbase;
                float acc[32];
#pragma unroll
                for (int t = 0; t < 32; t++) acc[t] = 0.f;
#pragma unroll 8
                for (int c4 = 0; c4 < 32; c4++) {
                    float4 wv = *(const float4*)(wr + c4 * 4);
#pragma unroll
                    for (int t = 0; t < 32; t++) {
                        float4 uv = Ul[t * 32 + c4];
                        acc[t] = fmaf(wv.x, uv.x, acc[t]);
                        acc[t] = fmaf(wv.y, uv.y, acc[t]);
                        acc[t] = fmaf(wv.z, uv.z, acc[t]);
                        acc[t] = fmaf(wv.w, uv.w, acc[t]);
                    }
                }
                float* zo = zxp + ks * ZX_SL + j;
#pragma unroll
                for (int t = 0; t < 32; t++) zo[t * DPROJ] = acc[t];
            }
            __syncthreads();
        }
        grid.sync();

        // -- 3b: conv + silu + SSM scan + gate (wave = one (head,p) group) --
        {
            float* BC = lds;                 // [32][256]
            float* ps_l = lds + 8192;        // [32]
            {   // B/C channels: conv-space c = 2048+tid -> zx col 4096+tid (same for all blocks)
                const int c = 2048 + tid, col = 4096 + tid;
                const float q0 = convw[c * 4], q1 = convw[c * 4 + 1], q2 = convw[c * 4 + 2], q3 = convw[c * 4 + 3];
                const float cb = convb[c];
                float xm3 = 0.f, xm2 = 0.f, xm1 = 0.f;
                for (int t = 0; t < T_DIM; t++) {
                    float x0 = zxr(zxp, t * DPROJ + col);
                    float v = fmaf(xm3, q0, fmaf(xm2, q1, fmaf(xm1, q2, fmaf(x0, q3, cb))));
                    BC[t * 256 + tid] = siluf(v);
                    xm3 = xm2; xm2 = xm1; xm1 = x0;
                }
            }
            __syncthreads();
            for (int hpb = bi; hpb < 512; hpb += NBv) {
                const int hp = hpb * 4 + wid;    // 0..2047
                const int head = hp >> 6;
                const int t0 = lane & 31;
                if (tid < T_DIM) ps_l[tid] = 0.f;
                __syncthreads();
                float dtv, dAv, xhv;
                {
                    float draw = zxr(zxp, t0 * DPROJ + 4352 + head) + dtb[head];
                    dtv = softplusf(draw);
                    dAv = expf(dtv * (-expf(Alog[head])));
                    const int c = hp;
                    const float q0 = convw[c * 4], q1 = convw[c * 4 + 1], q2 = convw[c * 4 + 2], q3 = convw[c * 4 + 3];
                    float a = fmaf(zxr(zxp, t0 * DPROJ + 2048 + c), q3, convb[c]);
                    if (t0 >= 1) a = fmaf(zxr(zxp, (t0 - 1) * DPROJ + 2048 + c), q2, a);
                    if (t0 >= 2) a = fmaf(zxr(zxp, (t0 - 2) * DPROJ + 2048 + c), q1, a);
                    if (t0 >= 3) a = fmaf(zxr(zxp, (t0 - 3) * DPROJ + 2048 + c), q0, a);
                    xhv = siluf(a);
                }
                const float coef = dtv * xhv;
                float h0 = 0.f, h1 = 0.f, ykeep = 0.f;
                for (int t = 0; t < T_DIM; t++) {
                    float dA_t = __shfl(dAv, t, 64);
                    float cf = __shfl(coef, t, 64);
                    float B0 = BC[t * 256 + lane], B1 = BC[t * 256 + 64 + lane];
                    float C0 = BC[t * 256 + 128 + lane], C1 = BC[t * 256 + 192 + lane];
                    h0 = fmaf(h0, dA_t, cf * B0);
                    h1 = fmaf(h1, dA_t, cf * B1);
                    float part = wave_sum(fmaf(h0, C0, h1 * C1));
                    if (lane == t) ykeep = part;
                }
                if (lane < T_DIM) {
                    float y = fmaf(Dp[head], xhv, ykeep);
                    float z = zxr(zxp, t0 * DPROJ + hp);
                    float g = y * siluf(z);
                    yg[t0 * D_INNER + hp] = g;
                    atomicAdd(&ps_l[t0], g * g);
                }
                __syncthreads();
                if (tid < T_DIM) psum[hpb * T_DIM + tid] = ps_l[tid];
            }
        }
        grid.sync();

        // -- 3c: Wout partials with fused RMSNorm scale: outp[ks][t][j] --
        {
            float4* Ul = (float4*)lds;       // [32][16] float4 = lds[0..2048)
            float* scale_s = lds + 2048;     // [32]
            float* ps8 = lds + 2080;         // [8][32]
            {
                const int t = tid & 31, bc = tid >> 5;
                float s = 0.f;
                for (int bb = bc; bb < 512; bb += 8) s += psum[bb * 32 + t];
                ps8[bc * 32 + t] = s;
            }
            __syncthreads();
            if (tid < 32) {
                float tot = 0.f;
#pragma unroll
                for (int i = 0; i < 8; i++) tot += ps8[i * 32 + tid];
                scale_s[tid] = 1.f / sqrtf(tot * (1.f / (float)D_INNER) + 1e-5f);
            }
            __syncthreads();
            for (int vb = bi; vb < 128; vb += NBv) {  // 32 k-slices * 4 j-blocks
                const int ks = vb >> 2, jb = vb & 3;
                const int kbase = ks * 64;
                for (int i = tid; i < 512; i += 256) {
                    const int t = i >> 4, c4 = i & 15;
                    const int k = kbase + c4 * 4;
                    float4 v = *(const float4*)(yg + t * D_INNER + k);
                    float4 nv = *(const float4*)(nw + k);
                    const float sc = scale_s[t];
                    v.x *= sc * nv.x; v.y *= sc * nv.y; v.z *= sc * nv.z; v.w *= sc * nv.w;
                    Ul[i] = v;
                }
                __syncthreads();
                const int j = jb * 256 + tid;    // < 1024 always
                const float* wr = Wout + (size_t)j * D_INNER + kbase;
                float acc[32];
#pragma unroll
                for (int t = 0; t < 32; t++) acc[t] = 0.f;
#pragma unroll 8
                for (int c4 = 0; c4 < 16; c4++) {
                    float4 wv = *(const float4*)(wr + c4 * 4);
#pragma unroll
                    for (int t = 0; t < 32; t++) {
                        float4 uv = Ul[t * 16 + c4];
                        acc[t] = fmaf(wv.x, uv.x, acc[t]);
                        acc[t] = fmaf(wv.y, uv.y, acc[t]);
                        acc[t] = fmaf(wv.z, uv.z, acc[t]);
                        acc[t] = fmaf(wv.w, uv.w, acc[t]);
                    }
                }
                float* oo = outp + ks * OUT_SL + j;
#pragma unroll
                for (int t = 0; t < 32; t++) oo[t * H_DIM] = acc[t];
                __syncthreads();
            }
        }
        grid.sync();
    }

    // ---- reduce final layer's Wout partials -> seqA (flat 32768) ----
    for (int i = gtid; i < 32768; i += NBv * 256) {
        float s = 0.f;
#pragma unroll 8
        for (int sl = 0; sl < 32; sl++) s += outp[sl * OUT_SL + i];
        seqA[i] = s;
    }
    grid.sync();

    // ---- S4: a3 = relu(w3 @ seq + b3)  (1024 rows, K=32768; block per row) ----
    {
        float* ws4 = lds;
        for (int row = bi; row < H_DIM; row += NBv) {
            const float* wr = w3 + (size_t)row * 32768;
            float acc = 0.f;
#pragma unroll 4
            for (int k = tid * 4; k < 32768; k += 1024) {
                float4 wv = *(const float4*)(wr + k);
                float4 xv = *(const float4*)(seqA + k);
                acc += wv.x * xv.x + wv.y * xv.y + wv.z * xv.z + wv.w * xv.w;
            }
            acc = wave_sum(acc);
            __syncthreads();
            if (lane == 0) ws4[wid] = acc;
            __syncthreads();
            if (tid == 0) a3v[row] = fmaxf(ws4[0] + ws4[1] + ws4[2] + ws4[3] + b3[row], 0.f);
        }
    }
    grid.sync();

    // ---- S5: out = sigmoid(w4 @ a3 + b4)  (16384 rows, K=1024; 2-row interleave) ----
    for (int r = gw; r < 16384; r += 2 * NW) {
        const int r2 = r + NW;
        const bool has2 = r2 < 16384;
        const float* wr0 = w4 + (size_t)r * H_DIM;
        const float* wr1 = w4 + (size_t)(has2 ? r2 : r) * H_DIM;
        float a0 = 0.f, a1 = 0.f;
        for (int k = lane * 4; k < H_DIM; k += 256) {
            float4 xv = *(const float4*)(a3v + k);
            float4 v0 = *(const float4*)(wr0 + k);
            float4 v1 = *(const float4*)(wr1 + k);
            a0 += v0.x * xv.x + v0.y * xv.y + v0.z * xv.z + v0.w * xv.w;
            a1 += v1.x * xv.x + v1.y * xv.y + v1.z * xv.z + v1.w * xv.w;
        }
        a0 = wave_sum(a0); a1 = wave_sum(a1);
        if (lane == 0) {
            out[r] = sigf(a0 + b4[r]);
            if (has2) out[r2] = sigf(a1 + b4[r2]);
        }
    }
}

extern "C" void kernel_launch(void* const* d_in, const int* in_sizes, int n_in,
                              void* d_out, int out_size, void* d_ws, size_t ws_size,
                              hipStream_t stream) {
    const float* x = (const float*)d_in[0];
    const float* w1 = (const float*)d_in[1];
    const float* b1 = (const float*)d_in[2];
    const float* w2 = (const float*)d_in[3];
    const float* b2 = (const float*)d_in[4];
    const float* mWin = (const float*)d_in[5];
    const float* mconvw = (const float*)d_in[6];
    const float* mconvb = (const float*)d_in[7];
    const float* mdtb = (const float*)d_in[8];
    const float* mAlog = (const float*)d_in[9];
    const float* mD = (const float*)d_in[10];
    const float* mnw = (const float*)d_in[11];
    const float* mWout = (const float*)d_in[12];
    const float* w3 = (const float*)d_in[13];
    const float* b3 = (const float*)d_in[14];
    const float* w4 = (const float*)d_in[15];
    const float* b4 = (const float*)d_in[16];
    float* out = (float*)d_out;
    float* ws = (float*)d_ws;

    // Size the cooperative grid to what is guaranteed co-resident (deterministic
    // per build, so every call launches the identical grid — capture-safe).
    int dev = 0;
    hipGetDevice(&dev);
    int cu = 256;
    if (hipDeviceGetAttribute(&cu, hipDeviceAttributeMultiprocessorCount, dev) != hipSuccess || cu < 1)
        cu = 256;
    int mb = 1;
    if (hipOccupancyMaxActiveBlocksPerMultiprocessor(&mb, (const void*)mega, 256, 0) != hipSuccess || mb < 1)
        mb = 1;
    long nb = (long)mb * (long)cu;
    if (nb > 1024) nb = 1024;
    if (nb < 1) nb = 1;

    void* args[] = {&x, &w1, &b1, &w2, &b2, &mWin, &mconvw, &mconvb, &mdtb, &mAlog,
                    &mD, &mnw, &mWout, &w3, &b3, &w4, &b4, &out, &ws};
    hipLaunchCooperativeKernel((void*)mega, dim3((unsigned)nb), dim3(256), args, 0, stream);
}